// Round 3
// baseline (249.355 us; speedup 1.0000x reference)
//
#include <hip/hip_runtime.h>

#define LOG2E 1.4426950408889634f

typedef float  f32x4 __attribute__((ext_vector_type(4)));
typedef int    i32x4 __attribute__((ext_vector_type(4)));
typedef short  s16x8 __attribute__((ext_vector_type(8)));

static __device__ __forceinline__ float exp2_fast(float x) {
#if __has_builtin(__builtin_amdgcn_exp2f)
    return __builtin_amdgcn_exp2f(x);
#else
    return exp2f(x);
#endif
}
static __device__ __forceinline__ unsigned short bf16_rne(float f) {
    unsigned u = __float_as_uint(f);
    u += 0x7FFFu + ((u >> 16) & 1u);
    return (unsigned short)(u >> 16);
}

// ---------------------------------------------------------------------------
// K_c: x (f32) -> bf16 canonical copy.
// ---------------------------------------------------------------------------
__global__ __launch_bounds__(256) void conv_x(
    const float* __restrict__ xf, unsigned short* __restrict__ xc)
{
    int i = blockIdx.x * 256 + threadIdx.x;
    xc[i] = bf16_rne(xf[i]);
}

// ---------------------------------------------------------------------------
// K0: W (f32) -> bf16 transposed Wt[h][o][K] so MFMA B-fragments are
// contiguous 16B loads.
// ---------------------------------------------------------------------------
__global__ __launch_bounds__(256) void prep_kernel(
    const float* __restrict__ W0, const float* __restrict__ W1,
    const float* __restrict__ W2,
    unsigned short* __restrict__ W0t, unsigned short* __restrict__ W1t,
    unsigned short* __restrict__ W2t)
{
    int gid = blockIdx.x * 256 + threadIdx.x;
    if (gid < 32768) {                      // W0: (4,128,64)
        int h = gid >> 13, d = (gid >> 6) & 127, o = gid & 63;
        W0t[(h * 64 + o) * 128 + d] = bf16_rne(W0[gid]);
    } else if (gid < 98304) {               // W1: (4,256,64)
        int g = gid - 32768;
        int h = g >> 14, d = (g >> 6) & 255, o = g & 63;
        W1t[(h * 64 + o) * 256 + d] = bf16_rne(W1[g]);
    } else if (gid < 114688) {              // W2: (1,256,64)
        int g = gid - 98304;
        int d = g >> 6, o = g & 63;
        W2t[o * 256 + d] = bf16_rne(W2[g]);
    }
}

// ---------------------------------------------------------------------------
// K1: adj (int32, 64MB) -> bitmask (2MB). One wave = 64 consecutive elements.
// ---------------------------------------------------------------------------
__global__ __launch_bounds__(256) void mk_bits(
    const int* __restrict__ adj, unsigned long long* __restrict__ bits)
{
    int idx = blockIdx.x * 256 + threadIdx.x;
    unsigned long long m = __ballot(adj[idx] != 0);
    if ((idx & 63) == 0) bits[idx >> 6] = m;
}

// ---------------------------------------------------------------------------
// K2 (per layer): h = X @ W  (MFMA 16x16x32 bf16) -> hT[h][o][n] (bf16),
// fused el2/er2 = (h.a_l)*log2e, (h.a_r)*log2e  (a read as f32).
// Wave = 16 rows x 64 cols, block = 4 waves, grid = (N/64, H).
// ---------------------------------------------------------------------------
__global__ __launch_bounds__(256) void gemm_elr(
    const unsigned short* __restrict__ X, int K,
    const unsigned short* __restrict__ Wt,   // [H][64][K] bf16
    const float* __restrict__ a,             // [H][128] f32 (a_l | a_r)
    unsigned short* __restrict__ hT,         // [H][64][4096]
    float* __restrict__ el2, float* __restrict__ er2)   // [H][4096]
{
    const int lane = threadIdx.x & 63, w = threadIdx.x >> 6;
    const int c = lane & 15, q = lane >> 4;
    const int h = blockIdx.y;
    const int nb = blockIdx.x * 64 + w * 16;
    const unsigned short* xrow = X + (size_t)(nb + c) * K + q * 8;
    const unsigned short* wb   = Wt + ((size_t)h * 64 + c) * K + q * 8;

    f32x4 acc[4] = {{0,0,0,0},{0,0,0,0},{0,0,0,0},{0,0,0,0}};
    for (int kk = 0; kk < K; kk += 32) {
        s16x8 af = *(const s16x8*)(xrow + kk);
#pragma unroll
        for (int j = 0; j < 4; ++j) {
            s16x8 bf = *(const s16x8*)(wb + (size_t)(j * 16) * K + kk);
            acc[j] = __builtin_amdgcn_mfma_f32_16x16x32_bf16(af, bf, acc[j], 0, 0, 0);
        }
    }
    // C/D layout: col = lane&15, row = q*4 + reg  ->  hT[h][o][n]
#pragma unroll
    for (int j = 0; j < 4; ++j) {
        unsigned d0 = (unsigned)bf16_rne(acc[j][0]) | ((unsigned)bf16_rne(acc[j][1]) << 16);
        unsigned d1 = (unsigned)bf16_rne(acc[j][2]) | ((unsigned)bf16_rne(acc[j][3]) << 16);
        unsigned short* dst = hT + ((size_t)h * 64 + j * 16 + c) * 4096 + nb + q * 4;
        ((unsigned*)dst)[0] = d0;
        ((unsigned*)dst)[1] = d1;
    }
    // el/er: dot C-tile rows with a_l/a_r, butterfly-reduce over the 16 c-lanes
    const float* ab = a + h * 128;
    float elr[4] = {0,0,0,0}, err[4] = {0,0,0,0};
#pragma unroll
    for (int j = 0; j < 4; ++j) {
        float al = ab[j * 16 + c];
        float ar = ab[64 + j * 16 + c];
#pragma unroll
        for (int r = 0; r < 4; ++r) {
            elr[r] = fmaf(al, acc[j][r], elr[r]);
            err[r] = fmaf(ar, acc[j][r], err[r]);
        }
    }
#pragma unroll
    for (int m = 1; m <= 8; m <<= 1) {
#pragma unroll
        for (int r = 0; r < 4; ++r) {
            elr[r] += __shfl_xor(elr[r], m, 64);
            err[r] += __shfl_xor(err[r], m, 64);
        }
    }
    if (c == 0) {
#pragma unroll
        for (int r = 0; r < 4; ++r) {
            int n = nb + q * 4 + r;
            el2[h * 4096 + n] = elr[r] * LOG2E;
            er2[h * 4096 + n] = err[r] * LOG2E;
        }
    }
}

// ---------------------------------------------------------------------------
// K2b: per-head max of er2 (deterministic). grid = (H), block = 256.
// ---------------------------------------------------------------------------
__global__ __launch_bounds__(256) void hmax_kernel(
    const float* __restrict__ er2, float* __restrict__ Mx)
{
    __shared__ float red[4];
    const int h = blockIdx.x, tid = threadIdx.x;
    float m = -3.0e38f;
#pragma unroll
    for (int i = 0; i < 16; ++i)
        m = fmaxf(m, er2[h * 4096 + i * 256 + tid]);
#pragma unroll
    for (int s = 1; s <= 32; s <<= 1)
        m = fmaxf(m, __shfl_xor(m, s, 64));
    if ((tid & 63) == 0) red[tid >> 6] = m;
    __syncthreads();
    if (tid == 0) {
        float r = fmaxf(fmaxf(red[0], red[1]), fmaxf(red[2], red[3]));
        Mx[h] = r;
    }
}

// ---------------------------------------------------------------------------
// K3 (per layer): fused masked-softmax attention, no rescaling.
//   p[n][m] = exp2( min(0, score2[n][m] - C2[n]) ) & adjbit   (p <= 1)
//   numerator += p @ h (MFMA bf16); denominator via ones-column MFMA.
// Block: 4 waves x 16 query rows = 64 rows, one head, one key-split segment.
// LDS: hT tile 64(o) x 256(m) bf16, row stride 264. grid = (64, H, KS).
// ---------------------------------------------------------------------------
__global__ __launch_bounds__(256) void att_kernel(
    const unsigned short* __restrict__ hT,
    const float* __restrict__ el2g, const float* __restrict__ er2g,
    const float* __restrict__ Mx,
    const unsigned long long* __restrict__ bits,
    float* __restrict__ accP, float* __restrict__ lP,
    int H, int KPS, int HO)
{
    __shared__ unsigned short ldsH[64 * 264];
    __shared__ float ldsE[256];
    const int tid = threadIdx.x;
    const int lane = tid & 63, w = tid >> 6;
    const int c = lane & 15, q = lane >> 4, q8 = q * 8;
    const int h = blockIdx.y, ks = blockIdx.z;
    const int nb = blockIdx.x * 64 + w * 16;
    const int rowA = nb + c;

    // per-row shift (log2 domain; leaky commutes with positive scale):
    // C2 = leaky(el2 + max_m er2) >= all scores of this row
    float M2 = Mx[h];
    float e2 = el2g[h * 4096 + rowA];
    float xx = e2 + M2;
    float C2 = fmaxf(xx, 0.2f * xx);
    const float elA = e2 - C2;
    const float elB = fmaf(0.2f, e2, -C2);

    const char* bitrow = (const char*)bits + (size_t)rowA * 512 + (size_t)(KPS >> 3) * ks;

    s16x8 ones = {0,0,0,0,0,0,0,0};
    if (c == 0) {
#pragma unroll
        for (int i = 0; i < 8; ++i) ones[i] = (short)0x3F80;   // bf16 1.0, col 0
    }
    f32x4 acc[4] = {{0,0,0,0},{0,0,0,0},{0,0,0,0},{0,0,0,0}};
    f32x4 accl = {0,0,0,0};

    const unsigned short* hTh = hT + (size_t)h * 64 * 4096;
    const float* erh = er2g + h * 4096;
    const int tiles = KPS >> 8;

    for (int t = 0; t < tiles; ++t) {
        const int mabs = ks * KPS + t * 256;
#pragma unroll
        for (int i = 0; i < 8; ++i) {
            int cidx = i * 256 + tid;
            int o = cidx >> 5, seg = cidx & 31;
            i32x4 v = *(const i32x4*)(hTh + (size_t)o * 4096 + mabs + seg * 8);
            *(i32x4*)(ldsH + o * 264 + seg * 8) = v;
        }
        if (tid < 64)
            *(f32x4*)(ldsE + tid * 4) = *(const f32x4*)(erh + mabs + tid * 4);
        __syncthreads();

        i32x4 b0 = *(const i32x4*)(bitrow + t * 32);
        i32x4 b1 = *(const i32x4*)(bitrow + t * 32 + 16);
        int bw[8] = {b0[0], b0[1], b0[2], b0[3], b1[0], b1[1], b1[2], b1[3]};

#pragma unroll
        for (int cc = 0; cc < 8; ++cc) {
            const int kl = cc * 32 + q8;
            f32x4 ea = *(const f32x4*)(ldsE + kl);
            f32x4 eb = *(const f32x4*)(ldsE + kl + 4);
            const unsigned word = (unsigned)bw[cc];
            unsigned pd[4];
#pragma unroll
            for (int jj = 0; jj < 4; ++jj) {
                float er0 = (jj < 2) ? ea[2 * jj]     : eb[2 * jj - 4];
                float er1 = (jj < 2) ? ea[2 * jj + 1] : eb[2 * jj - 3];
                float s0 = fminf(fmaxf(elA + er0, fmaf(0.2f, er0, elB)), 0.f);
                float s1 = fminf(fmaxf(elA + er1, fmaf(0.2f, er1, elB)), 0.f);
                float p0 = exp2_fast(s0);
                float p1 = exp2_fast(s1);
                unsigned m0 = (unsigned)(-(int)((word >> (q8 + 2 * jj)) & 1u));
                unsigned m1 = (unsigned)(-(int)((word >> (q8 + 2 * jj + 1)) & 1u));
                unsigned u0 = __float_as_uint(p0) & m0;
                unsigned u1 = __float_as_uint(p1) & m1;
                pd[jj] = (u0 >> 16) | (u1 & 0xFFFF0000u);  // truncate-pack 2 bf16
            }
            union { unsigned u[4]; s16x8 s; } afu;
            afu.u[0] = pd[0]; afu.u[1] = pd[1]; afu.u[2] = pd[2]; afu.u[3] = pd[3];
            s16x8 af = afu.s;
            const unsigned short* lb = ldsH + c * 264 + kl;
#pragma unroll
            for (int j = 0; j < 4; ++j) {
                s16x8 bf = *(const s16x8*)(lb + (size_t)(j * 16) * 264);
                acc[j] = __builtin_amdgcn_mfma_f32_16x16x32_bf16(af, bf, acc[j], 0, 0, 0);
            }
            accl = __builtin_amdgcn_mfma_f32_16x16x32_bf16(af, ones, accl, 0, 0, 0);
        }
        __syncthreads();
    }
    // denominator: column 0 of accl (lanes c==0), rows q*4+r
    float ls[4];
#pragma unroll
    for (int r = 0; r < 4; ++r) ls[r] = __shfl(accl[r], lane & 48, 64);

    float* ap = accP + ((size_t)ks * 4096 + nb + q * 4) * HO + h * 64 + c;
#pragma unroll
    for (int r = 0; r < 4; ++r)
#pragma unroll
        for (int j = 0; j < 4; ++j)
            ap[(size_t)r * HO + j * 16] = acc[j][r];
    if (c == 0) {
#pragma unroll
        for (int r = 0; r < 4; ++r)
            lP[((size_t)ks * H + h) * 4096 + nb + q * 4 + r] = ls[r];
    }
}

// ---------------------------------------------------------------------------
// K4: combine key-split partials, divide, optional ELU.
// Internal layers write bf16 (outb); final layer writes f32 (outf).
// ---------------------------------------------------------------------------
__global__ __launch_bounds__(256) void comb_kernel(
    const float* __restrict__ accP, const float* __restrict__ lP,
    unsigned short* __restrict__ outb, float* __restrict__ outf,
    int KS, int H, int lgHO, int do_elu)
{
    const int idx = blockIdx.x * 256 + threadIdx.x;
    const int HO = 1 << lgHO;
    const int n = idx >> lgHO, col = idx & (HO - 1), h = col >> 6;
    float s = 0.f, l = 0.f;
    for (int ks = 0; ks < KS; ++ks) {
        s += accP[((size_t)ks * 4096 + n) * HO + col];
        l += lP[((size_t)ks * H + h) * 4096 + n];
    }
    float v = s / l;
    if (do_elu && v < 0.f) v = exp2_fast(v * LOG2E) - 1.f;
    if (outf) outf[idx] = v;
    else      outb[idx] = bf16_rne(v);
}

// ---------------------------------------------------------------------------
extern "C" void kernel_launch(void* const* d_in, const int* in_sizes, int n_in,
                              void* d_out, int out_size, void* d_ws, size_t ws_size,
                              hipStream_t stream)
{
    (void)in_sizes; (void)n_in; (void)out_size; (void)ws_size;
    const float* x   = (const float*)d_in[0];
    const int*   adj = (const int*)d_in[1];
    const float* W0  = (const float*)d_in[2];
    const float* a0  = (const float*)d_in[3];
    const float* W1  = (const float*)d_in[4];
    const float* a1  = (const float*)d_in[5];
    const float* W2  = (const float*)d_in[6];
    const float* a2  = (const float*)d_in[7];

    char* p = (char*)d_ws;                                   // 15.5 MB used
    unsigned long long* bits = (unsigned long long*)(p + 0x000000);  // 2 MB
    unsigned short* hT  = (unsigned short*)(p + 0x200000);           // 2 MB
    unsigned short* X12 = (unsigned short*)(p + 0x400000);           // 2 MB
    unsigned short* Xc  = (unsigned short*)(p + 0x600000);           // 1 MB
    unsigned short* W0t = (unsigned short*)(p + 0x700000);           // 64 KB
    unsigned short* W1t = (unsigned short*)(p + 0x710000);           // 128 KB
    unsigned short* W2t = (unsigned short*)(p + 0x730000);           // 32 KB
    float*    el2  = (float*)(p + 0x738000);                         // 64 KB
    float*    er2  = (float*)(p + 0x748000);                         // 64 KB
    float*    Mx   = (float*)(p + 0x758000);                         // 64 B
    float*    accP = (float*)(p + 0x760000);                         // 8 MB
    float*    lP   = (float*)(p + 0xF60000);                         // 128 KB

    conv_x<<<2048, 256, 0, stream>>>(x, Xc);
    prep_kernel<<<448, 256, 0, stream>>>(W0, W1, W2, W0t, W1t, W2t);
    mk_bits<<<65536, 256, 0, stream>>>(adj, bits);

    // layer 0: K=128, H=4
    gemm_elr<<<dim3(64, 4), 256, 0, stream>>>(Xc, 128, W0t, a0, hT, el2, er2);
    hmax_kernel<<<4, 256, 0, stream>>>(er2, Mx);
    att_kernel<<<dim3(64, 4, 2), 256, 0, stream>>>(hT, el2, er2, Mx, bits, accP, lP, 4, 2048, 256);
    comb_kernel<<<4096, 256, 0, stream>>>(accP, lP, X12, nullptr, 2, 4, 8, 1);

    // layer 1: K=256, H=4
    gemm_elr<<<dim3(64, 4), 256, 0, stream>>>(X12, 256, W1t, a1, hT, el2, er2);
    hmax_kernel<<<4, 256, 0, stream>>>(er2, Mx);
    att_kernel<<<dim3(64, 4, 2), 256, 0, stream>>>(hT, el2, er2, Mx, bits, accP, lP, 4, 2048, 256);
    comb_kernel<<<4096, 256, 0, stream>>>(accP, lP, X12, nullptr, 2, 4, 8, 1);

    // layer 2: K=256, H=1, output f32 (no ELU)
    gemm_elr<<<dim3(64, 1), 256, 0, stream>>>(X12, 256, W2t, a2, hT, el2, er2);
    hmax_kernel<<<1, 256, 0, stream>>>(er2, Mx);
    att_kernel<<<dim3(64, 1, 4), 256, 0, stream>>>(hT, el2, er2, Mx, bits, accP, lP, 1, 1024, 64);
    comb_kernel<<<1024, 256, 0, stream>>>(accP, lP, nullptr, (float*)d_out, 4, 1, 6, 0);
}